// Round 6
// baseline (5144.122 us; speedup 1.0000x reference)
//
#include <hip/hip_runtime.h>

// B=2048, T=128, N=64, H=128
// inputs: 0 X(2048,128,64) 1 W_attn1(128,384) 2 b_attn1(128) 3 w_attn2(128)
//         4 b_attn2(1)[unused] 5 W_ih(512,64) 6 W_hh(512,128) 7 b_ih(512) 8 b_hh(512)
// output: (2048,128,128) f32
// ws (floats): Wt[128][128] @0 | W1T[256][128] @16384 | WcTp[192][128][4] @49152 | prex @147456
//
// k2 (R6): 512 blocks x 512 threads, 4 batches/block, prex(128KB) in LDS all 128 steps.
// vs R5: vector weight loads (b64/b128), conflict-free px reads (lane=row-position,
// no swizzle), shfl-based reductions (P2 k-reduce, P4 gate-reduce), c-state in
// registers, fewer/cheaper LDS round-trips. LDS total 159 KB.

typedef float f32x4 __attribute__((ext_vector_type(4)));
typedef float f32x2 __attribute__((ext_vector_type(2)));

#define LOG2E 1.44269504088896340736f
__device__ __forceinline__ float rcpf(float x){ return __builtin_amdgcn_rcpf(x); }
__device__ __forceinline__ float fast_exp(float x){ return __builtin_exp2f(x * LOG2E); }
__device__ __forceinline__ float fast_tanh(float x){
  float e = __builtin_exp2f(x * (2.0f * LOG2E));
  return 1.0f - 2.0f * rcpf(e + 1.0f);
}
__device__ __forceinline__ float fast_sig(float x){
  float e = __builtin_exp2f(x * (-LOG2E));
  return rcpf(1.0f + e);
}

// ---- packs ----
__global__ __launch_bounds__(256) void k0_wt(const float* __restrict__ Wat, float* __restrict__ Wt){
  int idx = blockIdx.x*256 + threadIdx.x;   // 16384
  int t = idx >> 7, k = idx & 127;
  Wt[idx] = Wat[k*384 + 256 + t];
}
__global__ __launch_bounds__(256) void k0_w1t(const float* __restrict__ Wat, float* __restrict__ W1T){
  int idx = blockIdx.x*256 + threadIdx.x;   // 32768 : W1T[c][k] = Wat[k][c]
  int c = idx >> 7, k = idx & 127;
  W1T[idx] = Wat[k*384 + c];
}
// WcTp[c][j][q] = W_q[j][c]  (q: 0=i,1=f,2=g,3=o; c<64 -> Wih, else Whh)
__global__ __launch_bounds__(256) void k0_wctp(const float* __restrict__ Wih, const float* __restrict__ Whh,
                                               float* __restrict__ WcTp){
  int idx = blockIdx.x*256 + threadIdx.x;   // 98304
  int c = idx >> 9, r = idx & 511, j = r >> 2, q = r & 3;
  int g = q*128 + j;
  WcTp[idx] = (c < 64) ? Wih[g*64 + c] : Whh[g*128 + (c-64)];
}

// ---- k1: prex[b][n][k] = sum_t X[b][t][n]*W1x[k][t] + b1[k] ----
__global__ __launch_bounds__(256) void k1_prex(const float* __restrict__ X,
                                               const float* __restrict__ Wt,
                                               const float* __restrict__ b1,
                                               float* __restrict__ prex){
  __shared__ float Xs[128][64];
  const int tid = threadIdx.x;
  const long b = blockIdx.x;
  {
    const float4* X4 = (const float4*)(X + b*8192);
    float4* Xs4 = (float4*)&Xs[0][0];
    #pragma unroll
    for (int i=0;i<8;i++) Xs4[tid + i*256] = X4[tid + i*256];
  }
  __syncthreads();
  const int nq = tid >> 4, kq = tid & 15;
  float acc[4][8];
  #pragma unroll
  for (int n=0;n<4;n++)
    #pragma unroll
    for (int k=0;k<8;k++) acc[n][k]=0.f;
  #pragma unroll 4
  for (int t=0;t<128;t++){
    float4 w0 = *(const float4*)(Wt + t*128 + kq*8);
    float4 w1 = *(const float4*)(Wt + t*128 + kq*8 + 4);
    float4 xv = *(const float4*)&Xs[t][nq*4];
    float wv[8] = {w0.x,w0.y,w0.z,w0.w,w1.x,w1.y,w1.z,w1.w};
    float xa[4] = {xv.x,xv.y,xv.z,xv.w};
    #pragma unroll
    for (int n=0;n<4;n++)
      #pragma unroll
      for (int k=0;k<8;k++) acc[n][k] = fmaf(xa[n], wv[k], acc[n][k]);
  }
  float4 bv0 = *(const float4*)(b1 + kq*8);
  float4 bv1 = *(const float4*)(b1 + kq*8 + 4);
  #pragma unroll
  for (int n=0;n<4;n++){
    float* dst = prex + (b*64 + nq*4 + n)*128 + kq*8;
    *(float4*)(dst)   = make_float4(acc[n][0]+bv0.x, acc[n][1]+bv0.y,
                                    acc[n][2]+bv0.z, acc[n][3]+bv0.w);
    *(float4*)(dst+4) = make_float4(acc[n][4]+bv1.x, acc[n][5]+bv1.y,
                                    acc[n][6]+bv1.z, acc[n][7]+bv1.w);
  }
}

// ---- k2 ----
__global__ __launch_bounds__(512, 2)
void k2_lstm(const float* __restrict__ X,
             const float* __restrict__ W1T,
             const float* __restrict__ WcTp,
             const float* __restrict__ w2,
             const float* __restrict__ bih,
             const float* __restrict__ bhh,
             const float* __restrict__ prex,
             float* __restrict__ out)
{
  const int tid = threadIdx.x;
  const long b0 = (long)blockIdx.x * 4;

  __shared__ float px[4][64][128];   // 128 KB, linear (reads are row-parallel)
  __shared__ float aap[8][4][128];   // P1 partials [cs][b][k]   16 KB
  __shared__ float epp[4][64][8];    // P2 partials [b][n][kq8]   8 KB
  __shared__ float actc[4][192];     // [0,64)=x_tilde, [64,192)=h  3 KB
  __shared__ float csd[4][128];      // c-state copy (for P1)      2 KB
  __shared__ float aa[4][128];       // attn pre-act h/c part      2 KB

  // ---- init state
  for (int i = tid; i < 4*192; i += 512) (&actc[0][0])[i] = 0.f;
  for (int i = tid; i < 4*128; i += 512) (&csd[0][0])[i] = 0.f;

  // ---- load px slice (linear, coalesced)
  {
    const f32x4* pg = (const f32x4*)prex + b0*2048;
    f32x4* pl = (f32x4*)&px[0][0][0];
    #pragma unroll
    for (int i = 0; i < 16; ++i) pl[tid + i*512] = pg[tid + i*512];
  }

  // ---- role constants
  // P1: kp = k-pair lane, cs = 8 slices of 32 c (wave-uniform: cs = wave id)
  const int p1_kp = tid & 63, p1_cs = tid >> 6;
  const float* p1_w = W1T + (p1_cs*32)*128 + p1_kp*2;
  const float* p1_src = (p1_cs < 4) ? &actc[0][64 + p1_cs*32]
                                    : &csd[0][(p1_cs-4)*32];
  const int p1_str = (p1_cs < 4) ? 192 : 128;

  // P1b / generic (b,k)
  const int g_b = tid >> 7, g_k = tid & 127;

  // P2: kq = quad position in row (lane-minor -> conflict-free), 4 n-slices
  const int p2_kq = tid & 31, p2_ns = (tid >> 5) & 3, p2_b = tid >> 7;
  const f32x4 w2v = *(const f32x4*)(w2 + p2_kq*4);   // loop-invariant

  // P4: cs = 4 c-slices of 48 (lanes 0..3), j = output unit
  const int p4_cs = tid & 3, p4_j = tid >> 2;
  const float* p4_w = WcTp + (p4_cs*48)*512 + p4_j*4;
  const float bq0 = bih[p4_j]       + bhh[p4_j];
  const float bq1 = bih[p4_j + 128] + bhh[p4_j + 128];
  const float bq2 = bih[p4_j + 256] + bhh[p4_j + 256];
  const float bq3 = bih[p4_j + 384] + bhh[p4_j + 384];
  float cre = 0.f;                                    // persistent c-state

  __syncthreads();

  for (int t = 0; t < 128; ++t) {
    // ---------- P1: aap[cs][b][kp*2..+2] = sum_{c in slice} hc[b][c]*W1[c][k]
    {
      f32x2 acc[4];
      #pragma unroll
      for (int b = 0; b < 4; ++b) { acc[b].x = 0.f; acc[b].y = 0.f; }
      #pragma unroll
      for (int g = 0; g < 8; ++g) {
        f32x4 h0 = *(const f32x4*)(p1_src + 0*p1_str + g*4);
        f32x4 h1 = *(const f32x4*)(p1_src + 1*p1_str + g*4);
        f32x4 h2 = *(const f32x4*)(p1_src + 2*p1_str + g*4);
        f32x4 h3 = *(const f32x4*)(p1_src + 3*p1_str + g*4);
        #pragma unroll
        for (int ii = 0; ii < 4; ++ii) {
          f32x2 w = *(const f32x2*)(p1_w + (g*4 + ii)*128);
          acc[0].x = fmaf(h0[ii], w.x, acc[0].x); acc[0].y = fmaf(h0[ii], w.y, acc[0].y);
          acc[1].x = fmaf(h1[ii], w.x, acc[1].x); acc[1].y = fmaf(h1[ii], w.y, acc[1].y);
          acc[2].x = fmaf(h2[ii], w.x, acc[2].x); acc[2].y = fmaf(h2[ii], w.y, acc[2].y);
          acc[3].x = fmaf(h3[ii], w.x, acc[3].x); acc[3].y = fmaf(h3[ii], w.y, acc[3].y);
        }
      }
      #pragma unroll
      for (int b = 0; b < 4; ++b)
        *(f32x2*)&aap[p1_cs][b][p1_kp*2] = acc[b];
    }
    __syncthreads();

    // ---------- P1b: aa[b][k] = sum_cs aap[cs][b][k]
    {
      float s = 0.f;
      #pragma unroll
      for (int cs = 0; cs < 8; ++cs) s += aap[cs][g_b][g_k];
      aa[g_b][g_k] = s;
    }
    __syncthreads();

    // ---------- P2: e-partials; lane kq owns quad kq of each row (conflict-free)
    {
      f32x4 av = *(const f32x4*)&aa[p2_b][p2_kq*4];
      #pragma unroll
      for (int i = 0; i < 16; ++i) {
        int n = p2_ns*16 + i;
        f32x4 p = *(const f32x4*)&px[p2_b][n][p2_kq*4];
        float e = fmaf(fast_tanh(p.x+av.x), w2v.x,
                  fmaf(fast_tanh(p.y+av.y), w2v.y,
                  fmaf(fast_tanh(p.z+av.z), w2v.z,
                       fast_tanh(p.w+av.w) * w2v.w)));
        e += __shfl_xor(e, 1, 64);
        e += __shfl_xor(e, 2, 64);
        if ((p2_kq & 3) == 0) epp[p2_b][n][p2_kq >> 2] = e;
      }
    }
    __syncthreads();

    // ---------- P3: reduce kq8, softmax over n, x_tilde -> actc[b][n]
    if (tid < 256) {
      int b = tid >> 6, n = tid & 63;
      f32x4 e0 = *(const f32x4*)&epp[b][n][0];
      f32x4 e1 = *(const f32x4*)&epp[b][n][4];
      float e = ((e0.x+e0.y)+(e0.z+e0.w)) + ((e1.x+e1.y)+(e1.z+e1.w));
      float mx = e;
      #pragma unroll
      for (int m=32;m>=1;m>>=1) mx = fmaxf(mx, __shfl_xor(mx,m,64));
      float p = fast_exp(e - mx);
      float sm = p;
      #pragma unroll
      for (int m=32;m>=1;m>>=1) sm += __shfl_xor(sm,m,64);
      actc[b][n] = p * rcpf(sm) * X[(b0+b)*8192 + (long)t*64 + n];
    }
    __syncthreads();

    // ---------- P4a: gates via 4-lane c-split; acc[b] over (i,f,g,o) of unit j
    f32x4 ac0, ac1, ac2, ac3;
    {
      ac0 = 0.f; ac1 = 0.f; ac2 = 0.f; ac3 = 0.f;
      const int cb = p4_cs*48;
      #pragma unroll
      for (int g = 0; g < 12; ++g) {
        f32x4 a0 = *(const f32x4*)&actc[0][cb + g*4];
        f32x4 a1 = *(const f32x4*)&actc[1][cb + g*4];
        f32x4 a2 = *(const f32x4*)&actc[2][cb + g*4];
        f32x4 a3 = *(const f32x4*)&actc[3][cb + g*4];
        #pragma unroll
        for (int ii = 0; ii < 4; ++ii) {
          f32x4 w = *(const f32x4*)(p4_w + (g*4 + ii)*512);
          ac0 += a0[ii] * w;
          ac1 += a1[ii] * w;
          ac2 += a2[ii] * w;
          ac3 += a3[ii] * w;
        }
      }
      // reduce over the 4 c-slices (adjacent lanes)
      #pragma unroll
      for (int m = 1; m <= 2; m <<= 1) {
        f32x4 r0, r1, r2, r3;
        r0.x=__shfl_xor(ac0.x,m,64); r0.y=__shfl_xor(ac0.y,m,64); r0.z=__shfl_xor(ac0.z,m,64); r0.w=__shfl_xor(ac0.w,m,64);
        r1.x=__shfl_xor(ac1.x,m,64); r1.y=__shfl_xor(ac1.y,m,64); r1.z=__shfl_xor(ac1.z,m,64); r1.w=__shfl_xor(ac1.w,m,64);
        r2.x=__shfl_xor(ac2.x,m,64); r2.y=__shfl_xor(ac2.y,m,64); r2.z=__shfl_xor(ac2.z,m,64); r2.w=__shfl_xor(ac2.w,m,64);
        r3.x=__shfl_xor(ac3.x,m,64); r3.y=__shfl_xor(ac3.y,m,64); r3.z=__shfl_xor(ac3.z,m,64); r3.w=__shfl_xor(ac3.w,m,64);
        ac0 += r0; ac1 += r1; ac2 += r2; ac3 += r3;
      }
    }
    // my batch = p4_cs; pointwise LSTM in registers
    float hn;
    {
      f32x4 gv = (p4_cs == 0) ? ac0 : (p4_cs == 1) ? ac1 : (p4_cs == 2) ? ac2 : ac3;
      float ig = fast_sig (gv.x + bq0);
      float fg = fast_sig (gv.y + bq1);
      float gg = fast_tanh(gv.z + bq2);
      float og = fast_sig (gv.w + bq3);
      cre = fmaf(fg, cre, ig*gg);
      hn  = og * fast_tanh(cre);
    }
    __syncthreads();   // all actc/csd reads of this step done

    // ---------- P4b: publish state + output
    csd[p4_cs][p4_j]        = cre;
    actc[p4_cs][64 + p4_j]  = hn;
    out[(b0 + p4_cs)*16384 + (long)t*128 + p4_j] = hn;
    __syncthreads();
  }
}

extern "C" void kernel_launch(void* const* d_in, const int* in_sizes, int n_in,
                              void* d_out, int out_size, void* d_ws, size_t ws_size,
                              hipStream_t stream) {
  const float* X   = (const float*)d_in[0];
  const float* Wat = (const float*)d_in[1];
  const float* b1  = (const float*)d_in[2];
  const float* w2  = (const float*)d_in[3];
  const float* Wih = (const float*)d_in[5];
  const float* Whh = (const float*)d_in[6];
  const float* bih = (const float*)d_in[7];
  const float* bhh = (const float*)d_in[8];
  float* out  = (float*)d_out;
  float* Wt   = (float*)d_ws;            // 16384
  float* W1T  = Wt + 16384;              // 32768
  float* WcTp = W1T + 32768;             // 98304
  float* prex = WcTp + 98304;            // 16777216

  k0_wt  <<<64,  256, 0, stream>>>(Wat, Wt);
  k0_w1t <<<128, 256, 0, stream>>>(Wat, W1T);
  k0_wctp<<<384, 256, 0, stream>>>(Wih, Whh, WcTp);
  k1_prex<<<2048,256, 0, stream>>>(X, Wt, b1, prex);
  k2_lstm<<<512, 512, 0, stream>>>(X, W1T, WcTp, w2, bih, bhh, prex, out);
}